// Round 13
// baseline (230.093 us; speedup 1.0000x reference)
//
#include <hip/hip_runtime.h>

#define NP    128
#define NITER 100
#define RSC   72.13475204444817f    // log2(e)/EPS, EPS=0.02
#define IRSC  0.013862943611198906f // EPS*ln2 = 1/RSC

typedef __attribute__((ext_vector_type(8))) short bf16x8;
typedef __attribute__((ext_vector_type(4))) float f32x4;

__device__ __forceinline__ float wsum64(float x) {
  #pragma unroll
  for (int s = 1; s < 64; s <<= 1) x += __shfl_xor(x, s);
  return x;
}
__device__ __forceinline__ float bf2f(unsigned short h) {
  return __uint_as_float(((unsigned)h) << 16);
}
__device__ __forceinline__ unsigned short f2bf(float f) {   // RNE
  unsigned u = __float_as_uint(f);
  u += 0x7fffu + ((u >> 16) & 1u);
  return (unsigned short)(u >> 16);
}

// Linear-domain Sinkhorn, FOUR WAVES PER PROBLEM (R11 structure) with the
// iteration critical path shortened:
//   * slack sums Sigma(Q)+q128 / Sigma(P)+p128 via MFMA with an all-ones
//     fragment + C-init (replaces two 6-deep shuffle-reduce chains)
//   * P/Q -> MFMA-fragment redistribution via 16 independent ds_bpermute
//     from lane-packed pairs (R10-verified formula)
//   Cross-wave traffic is ONLY Slds/Tlds; 2 barriers/iter.
// R12 bug fixed: pass1 Slds store restored to 32wv+16rt+4lg (the 4lg term
// was dropped -> rows 4..15 of each block unwritten -> poison -> NaN).
__global__ __launch_bounds__(256, 2) void emd_sinkhorn(
    const float* __restrict__ j1g, const float* __restrict__ j2g,
    float* __restrict__ out)
{
  __shared__ __align__(16) float x1s[NP], y1s[NP], x2s[NP], y2s[NP];
  __shared__ __align__(16) float ahs[NP], bhs[NP];
  __shared__ __align__(16) float Slds[NP];   // pass1 row sums
  __shared__ __align__(16) float Tlds[NP];   // pass2 col sums
  __shared__ float red[4];

  const int t  = threadIdx.x;        // 0..255
  const int l  = t & 63;             // lane
  const int wv = t >> 6;             // wave 0..3: owns rows/cols 32wv..32wv+31
  const int lg = l >> 4;             // k-group 0..3
  const int li = l & 15;             // tile row/col 0..15
  const int b  = blockIdx.x;
  const float* J1 = j1g + (size_t)b * (NP * 3);
  const float* J2 = j2g + (size_t)b * (NP * 3);

  // ---- load particles ----
  if (t < NP) {
    x1s[t] = J1[3*t]; y1s[t] = J1[3*t+1]; ahs[t] = J1[3*t+2];
    x2s[t] = J2[3*t]; y2s[t] = J2[3*t+1]; bhs[t] = J2[3*t+2];
  }
  __syncthreads();

  // ---- energies (raw weights; redundant per wave, deterministic) ----
  const float e1 = wsum64(ahs[l] + ahs[l + 64]);
  const float e2 = wsum64(bhs[l] + bhs[l + 64]);
  const float dE = fabsf(e2 - e1);
  const float aslk = fmaxf(fmaxf(e2 - e1, 0.0f), 1e-30f);
  const float bslk = fmaxf(fmaxf(e1 - e2, 0.0f), 1e-30f);
  const float2 araw = *(const float2*)&ahs[2*l];
  const float2 braw = *(const float2*)&bhs[2*l];
  const float ah0 = fmaxf(araw.x, 1e-30f), ah1 = fmaxf(araw.y, 1e-30f);
  const float bh0 = fmaxf(braw.x, 1e-30f), bh1 = fmaxf(braw.y, 1e-30f);

  // ---- build this wave's K fragments (once) ----
  bf16x8 KA[2][4], KB[2][4];
  #pragma unroll
  for (int rt = 0; rt < 2; ++rt) {
    const int n = 32*wv + 16*rt + li;
    const float xr = x1s[n], yr = y1s[n];
    #pragma unroll
    for (int kt = 0; kt < 4; ++kt) {
      #pragma unroll
      for (int i2 = 0; i2 < 8; ++i2) {
        const int k = 32*kt + 8*lg + i2;
        const float dx = x2s[k] - xr + 1e-12f;
        const float dy = y2s[k] - yr + 1e-12f;
        KA[rt][kt][i2] = (short)f2bf(
            __builtin_amdgcn_exp2f(-__builtin_sqrtf(dx*dx + dy*dy) * RSC));
      }
    }
  }
  #pragma unroll
  for (int ct = 0; ct < 2; ++ct) {
    const int m = 32*wv + 16*ct + li;
    const float xc = x2s[m], yc = y2s[m];
    #pragma unroll
    for (int kt = 0; kt < 4; ++kt) {
      #pragma unroll
      for (int i2 = 0; i2 < 8; ++i2) {
        const int k = 32*kt + 8*lg + i2;
        const float dx = xc - x1s[k] + 1e-12f;
        const float dy = yc - y1s[k] + 1e-12f;
        KB[ct][kt][i2] = (short)f2bf(
            __builtin_amdgcn_exp2f(-__builtin_sqrtf(dx*dx + dy*dy) * RSC));
      }
    }
  }

  // all-ones bf16 fragment (for slack-sum MFMAs)
  bf16x8 onef;
  #pragma unroll
  for (int i2 = 0; i2 < 8; ++i2) onef[i2] = (short)0x3F80;

  // ---- init: Q = 1 (g=0); lane l holds cols (2l, 2l+1) packed ----
  unsigned Qpk = 0x3F803F80u;
  unsigned Ppk = 0;
  float q128 = 1.0f;

  for (int it = 0; it < NITER; ++it) {
    // ---- gather Q fragments (register-only ds_bpermute; R10-verified) ----
    bf16x8 qf[4];
    #pragma unroll
    for (int kt = 0; kt < 4; ++kt) {
      union { unsigned u[4]; bf16x8 v; } r;
      #pragma unroll
      for (int q = 0; q < 4; ++q)
        r.u[q] = (unsigned)__builtin_amdgcn_ds_bpermute(
            4*(16*kt + 4*lg + q), (int)Qpk);
      qf[kt] = r.v;
    }

    // -------- pass1: s-rows(own 32) = K·Q + q128 ; s128 = ΣQ + q128 --------
    f32x4 acc[2], accS;
    accS = (f32x4){q128, q128, q128, q128};
    #pragma unroll
    for (int rt = 0; rt < 2; ++rt) acc[rt] = (f32x4){q128, q128, q128, q128};
    #pragma unroll
    for (int kt = 0; kt < 4; ++kt) {
      acc[0] = __builtin_amdgcn_mfma_f32_16x16x32_bf16(KA[0][kt], qf[kt], acc[0], 0, 0, 0);
      acc[1] = __builtin_amdgcn_mfma_f32_16x16x32_bf16(KA[1][kt], qf[kt], acc[1], 0, 0, 0);
      accS   = __builtin_amdgcn_mfma_f32_16x16x32_bf16(onef, qf[kt], accS, 0, 0, 0);
    }
    const float p128 = aslk * __builtin_amdgcn_rcpf(accS[0]);
    if (li == 0) {   // lanes 16*lg: hold D rows 4lg+reg (col 0)
      *(f32x4*)&Slds[32*wv + 4*lg]      = acc[0];
      *(f32x4*)&Slds[32*wv + 16 + 4*lg] = acc[1];
    }
    __syncthreads();   // BAR1: Slds complete

    // ---- P for rows (2l, 2l+1), redundant in every wave ----
    const float2 s2 = *(const float2*)&Slds[2*l];
    const float P0 = ah0 * __builtin_amdgcn_rcpf(s2.x);
    const float P1 = ah1 * __builtin_amdgcn_rcpf(s2.y);
    Ppk = (unsigned)f2bf(P0) | ((unsigned)f2bf(P1) << 16);

    // ---- gather P fragments ----
    bf16x8 pf[4];
    #pragma unroll
    for (int kt = 0; kt < 4; ++kt) {
      union { unsigned u[4]; bf16x8 v; } r;
      #pragma unroll
      for (int q = 0; q < 4; ++q)
        r.u[q] = (unsigned)__builtin_amdgcn_ds_bpermute(
            4*(16*kt + 4*lg + q), (int)Ppk);
      pf[kt] = r.v;
    }

    // -------- pass2: s'-cols(own 32) = K^T·P + p128 ; s'128 = ΣP + p128 ----
    f32x4 acc2[2], accS2;
    accS2 = (f32x4){p128, p128, p128, p128};
    #pragma unroll
    for (int ct = 0; ct < 2; ++ct) acc2[ct] = (f32x4){p128, p128, p128, p128};
    #pragma unroll
    for (int kt = 0; kt < 4; ++kt) {
      acc2[0] = __builtin_amdgcn_mfma_f32_16x16x32_bf16(pf[kt], KB[0][kt], acc2[0], 0, 0, 0);
      acc2[1] = __builtin_amdgcn_mfma_f32_16x16x32_bf16(pf[kt], KB[1][kt], acc2[1], 0, 0, 0);
      accS2   = __builtin_amdgcn_mfma_f32_16x16x32_bf16(pf[kt], onef, accS2, 0, 0, 0);
    }
    q128 = bslk * __builtin_amdgcn_rcpf(accS2[0]);
    if (lg == 0) {   // lanes 0..15: D rows identical (A replicated), col li
      Tlds[32*wv + li]      = acc2[0][0];
      Tlds[32*wv + 16 + li] = acc2[1][0];
    }
    __syncthreads();   // BAR2: Tlds complete

    // ---- Q for cols (2l, 2l+1), redundant in every wave ----
    const float2 t2 = *(const float2*)&Tlds[2*l];
    const float Q0 = bh0 * __builtin_amdgcn_rcpf(t2.x);
    const float Q1 = bh1 * __builtin_amdgcn_rcpf(t2.y);
    Qpk = (unsigned)f2bf(Q0) | ((unsigned)f2bf(Q1) << 16);
  }

  // ---- emd = sum_{n,m<128} d * P[n] Q[m] K[n][m] + dE ; d=-log2(K)*IRSC ----
  bf16x8 qf[4];
  #pragma unroll
  for (int kt = 0; kt < 4; ++kt) {
    union { unsigned u[4]; bf16x8 v; } r;
    #pragma unroll
    for (int q = 0; q < 4; ++q)
      r.u[q] = (unsigned)__builtin_amdgcn_ds_bpermute(
          4*(16*kt + 4*lg + q), (int)Qpk);
    qf[kt] = r.v;
  }
  float accE = 0.0f;
  #pragma unroll
  for (int rt = 0; rt < 2; ++rt) {
    const int n = 32*wv + 16*rt + li;
    const unsigned pr = (unsigned)__builtin_amdgcn_ds_bpermute(
        4*(n >> 1), (int)Ppk);
    const float Pn = bf2f((unsigned short)((li & 1) ? (pr >> 16) : pr));
    #pragma unroll
    for (int kt = 0; kt < 4; ++kt) {
      #pragma unroll
      for (int i2 = 0; i2 < 8; ++i2) {
        const float kk = bf2f((unsigned short)KA[rt][kt][i2]);
        const float qm = bf2f((unsigned short)qf[kt][i2]);
        const float d  = -__builtin_amdgcn_logf(kk) * IRSC;
        accE = fmaf(d, (Pn * kk) * qm, accE);
      }
    }
  }
  accE = wsum64(accE);
  if (l == 0) red[wv] = accE;
  __syncthreads();
  if (t == 0) out[b] = ((red[0] + red[1]) + (red[2] + red[3])) + dE;
}

extern "C" void kernel_launch(void* const* d_in, const int* in_sizes, int n_in,
                              void* d_out, int out_size, void* d_ws, size_t ws_size,
                              hipStream_t stream) {
  const float* j1 = (const float*)d_in[0];
  const float* j2 = (const float*)d_in[1];
  float* outp = (float*)d_out;
  const int batch = in_sizes[0] / (NP * 3);
  hipLaunchKernelGGL(emd_sinkhorn, dim3(batch), dim3(256), 0, stream,
                     j1, j2, outp);
}

// Round 14
// 196.176 us; speedup vs baseline: 1.1729x; 1.1729x over previous
//
#include <hip/hip_runtime.h>

#define NP    128
#define NITER 100
#define RSC   72.13475204444817f    // log2(e)/EPS, EPS=0.02
#define IRSC  0.013862943611198906f // EPS*ln2 = 1/RSC

typedef __attribute__((ext_vector_type(8))) short bf16x8;
typedef __attribute__((ext_vector_type(4))) float f32x4;

__device__ __forceinline__ float wsum64(float x) {
  #pragma unroll
  for (int s = 1; s < 64; s <<= 1) x += __shfl_xor(x, s);
  return x;
}
__device__ __forceinline__ float bf2f(unsigned short h) {
  return __uint_as_float(((unsigned)h) << 16);
}
__device__ __forceinline__ unsigned short f2bf(float f) {   // RNE
  unsigned u = __float_as_uint(f);
  u += 0x7fffu + ((u >> 16) & 1u);
  return (unsigned short)(u >> 16);
}

// Linear-domain Sinkhorn, FOUR WAVES PER PROBLEM — R11 structure verbatim
// (fastest passing variant, 201us), with occupancy doubled:
// launch_bounds(256,4): 128-reg cap vs R11's measured 108-reg allocation ->
// same codegen, but 4 blocks/CU resident => the whole 1024-block grid runs
// in ONE round with 4-way latency interleave per SIMD (R11's 2 barriers +
// 6 LDS accesses/iter spine was only 2-way hidden at (256,2)).
// R12/13 lesson: keep slack sums (wsum64 -> SP/SQ) OFF the spine — p128/q128
// are consumed from the PREVIOUS iteration's sums, overlapping the chains
// with the MFMA passes.
__global__ __launch_bounds__(256, 4) void emd_sinkhorn(
    const float* __restrict__ j1g, const float* __restrict__ j2g,
    float* __restrict__ out)
{
  __shared__ __align__(16) float x1s[NP], y1s[NP], x2s[NP], y2s[NP];
  __shared__ __align__(16) float ahs[NP], bhs[NP];
  __shared__ __align__(16) float Slds[NP];            // pass1 row sums
  __shared__ __align__(16) float Tlds[NP];            // pass2 col sums
  __shared__ __align__(16) unsigned short Plds[NP];   // bf16 P
  __shared__ __align__(16) unsigned short Qlds[NP];   // bf16 Q
  __shared__ float red[4];

  const int t  = threadIdx.x;        // 0..255
  const int l  = t & 63;             // lane
  const int wv = t >> 6;             // wave 0..3: owns rows/cols 32wv..32wv+31
  const int lg = l >> 4;             // k-group 0..3
  const int li = l & 15;             // tile row/col 0..15
  const int b  = blockIdx.x;
  const float* J1 = j1g + (size_t)b * (NP * 3);
  const float* J2 = j2g + (size_t)b * (NP * 3);

  // ---- load particles (threads 0..127) ----
  if (t < NP) {
    x1s[t] = J1[3*t]; y1s[t] = J1[3*t+1]; ahs[t] = J1[3*t+2];
    x2s[t] = J2[3*t]; y2s[t] = J2[3*t+1]; bhs[t] = J2[3*t+2];
  }
  __syncthreads();

  // ---- energies (raw weights; redundant per wave, deterministic) ----
  const float e1 = wsum64(ahs[l] + ahs[l + 64]);
  const float e2 = wsum64(bhs[l] + bhs[l + 64]);
  const float dE = fabsf(e2 - e1);
  const float aslk = fmaxf(fmaxf(e2 - e1, 0.0f), 1e-30f);
  const float bslk = fmaxf(fmaxf(e1 - e2, 0.0f), 1e-30f);
  const float2 araw = *(const float2*)&ahs[2*l];
  const float2 braw = *(const float2*)&bhs[2*l];
  const float ah0 = fmaxf(araw.x, 1e-30f), ah1 = fmaxf(araw.y, 1e-30f);
  const float bh0 = fmaxf(braw.x, 1e-30f), bh1 = fmaxf(braw.y, 1e-30f);

  // ---- build this wave's K fragments (once) ----
  bf16x8 KA[2][4], KB[2][4];
  #pragma unroll
  for (int rt = 0; rt < 2; ++rt) {
    const int n = 32*wv + 16*rt + li;
    const float xr = x1s[n], yr = y1s[n];
    #pragma unroll
    for (int kt = 0; kt < 4; ++kt) {
      #pragma unroll
      for (int i2 = 0; i2 < 8; ++i2) {
        const int k = 32*kt + 8*lg + i2;
        const float dx = x2s[k] - xr + 1e-12f;
        const float dy = y2s[k] - yr + 1e-12f;
        KA[rt][kt][i2] = (short)f2bf(
            __builtin_amdgcn_exp2f(-__builtin_sqrtf(dx*dx + dy*dy) * RSC));
      }
    }
  }
  #pragma unroll
  for (int ct = 0; ct < 2; ++ct) {
    const int m = 32*wv + 16*ct + li;
    const float xc = x2s[m], yc = y2s[m];
    #pragma unroll
    for (int kt = 0; kt < 4; ++kt) {
      #pragma unroll
      for (int i2 = 0; i2 < 8; ++i2) {
        const int k = 32*kt + 8*lg + i2;
        const float dx = xc - x1s[k] + 1e-12f;
        const float dy = yc - y1s[k] + 1e-12f;
        KB[ct][kt][i2] = (short)f2bf(
            __builtin_amdgcn_exp2f(-__builtin_sqrtf(dx*dx + dy*dy) * RSC));
      }
    }
  }

  // ---- init: Q = 1 (g=0); lane l holds (2l, 2l+1) packed ----
  ((unsigned*)Qlds)[l] = 0x3F803F80u;   // every wave writes same values
  float SQ = 128.0f, q128 = 1.0f;
  __syncthreads();

  for (int it = 0; it < NITER; ++it) {
    const float p128 = aslk * __builtin_amdgcn_rcpf(SQ + q128);

    // -------- pass1: s-rows(own 32) = K·Q + q128 --------
    bf16x8 qf[4];
    #pragma unroll
    for (int kt = 0; kt < 4; ++kt)
      qf[kt] = *(const bf16x8*)((const char*)Qlds + 64*kt + 16*lg);
    f32x4 acc[2];
    #pragma unroll
    for (int rt = 0; rt < 2; ++rt) {
      acc[rt] = (f32x4){q128, q128, q128, q128};
      #pragma unroll
      for (int kt = 0; kt < 4; ++kt)
        acc[rt] = __builtin_amdgcn_mfma_f32_16x16x32_bf16(
            KA[rt][kt], qf[kt], acc[rt], 0, 0, 0);
    }
    if (li == 0) {
      #pragma unroll
      for (int rt = 0; rt < 2; ++rt)
        *(f32x4*)&Slds[32*wv + 16*rt + 4*lg] = acc[rt];
    }
    __syncthreads();   // BAR1: Slds complete

    // ---- P for rows (2l, 2l+1), redundant in every wave ----
    const float2 s2 = *(const float2*)&Slds[2*l];
    const float P0 = ah0 * __builtin_amdgcn_rcpf(s2.x);
    const float P1 = ah1 * __builtin_amdgcn_rcpf(s2.y);
    const float SP = wsum64(P0 + P1);
    const float q128n = bslk * __builtin_amdgcn_rcpf(SP + p128);
    ((unsigned*)Plds)[l] = (unsigned)f2bf(P0) | ((unsigned)f2bf(P1) << 16);

    // -------- pass2: s'-cols(own 32) = K^T·P + p128 --------
    bf16x8 pf[4];
    #pragma unroll
    for (int kt = 0; kt < 4; ++kt)
      pf[kt] = *(const bf16x8*)((const char*)Plds + 64*kt + 16*lg);
    f32x4 acc2[2];
    #pragma unroll
    for (int ct = 0; ct < 2; ++ct) {
      acc2[ct] = (f32x4){p128, p128, p128, p128};
      #pragma unroll
      for (int kt = 0; kt < 4; ++kt)
        acc2[ct] = __builtin_amdgcn_mfma_f32_16x16x32_bf16(
            pf[kt], KB[ct][kt], acc2[ct], 0, 0, 0);
    }
    if (lg == 0) {
      #pragma unroll
      for (int ct = 0; ct < 2; ++ct)
        Tlds[32*wv + 16*ct + li] = acc2[ct][0];   // D rows identical
    }
    __syncthreads();   // BAR2: Tlds complete

    // ---- Q for cols (2l, 2l+1), redundant in every wave ----
    const float2 t2 = *(const float2*)&Tlds[2*l];
    const float Q0 = bh0 * __builtin_amdgcn_rcpf(t2.x);
    const float Q1 = bh1 * __builtin_amdgcn_rcpf(t2.y);
    SQ = wsum64(Q0 + Q1);
    ((unsigned*)Qlds)[l] = (unsigned)f2bf(Q0) | ((unsigned)f2bf(Q1) << 16);
    q128 = q128n;
  }

  // ---- emd = sum_{n,m<128} d * P[n] Q[m] K[n][m] + dE ; d=-log2(K)*IRSC ----
  bf16x8 qf[4];
  #pragma unroll
  for (int kt = 0; kt < 4; ++kt)
    qf[kt] = *(const bf16x8*)((const char*)Qlds + 64*kt + 16*lg);
  float accE = 0.0f;
  #pragma unroll
  for (int rt = 0; rt < 2; ++rt) {
    const float Pn = bf2f(Plds[32*wv + 16*rt + li]);
    #pragma unroll
    for (int kt = 0; kt < 4; ++kt) {
      #pragma unroll
      for (int i2 = 0; i2 < 8; ++i2) {
        const float kk = bf2f((unsigned short)KA[rt][kt][i2]);
        const float qm = bf2f((unsigned short)qf[kt][i2]);
        const float d  = -__builtin_amdgcn_logf(kk) * IRSC;
        accE = fmaf(d, (Pn * kk) * qm, accE);
      }
    }
  }
  accE = wsum64(accE);
  if (l == 0) red[wv] = accE;
  __syncthreads();
  if (t == 0) out[b] = ((red[0] + red[1]) + (red[2] + red[3])) + dE;
}

extern "C" void kernel_launch(void* const* d_in, const int* in_sizes, int n_in,
                              void* d_out, int out_size, void* d_ws, size_t ws_size,
                              hipStream_t stream) {
  const float* j1 = (const float*)d_in[0];
  const float* j2 = (const float*)d_in[1];
  float* outp = (float*)d_out;
  const int batch = in_sizes[0] / (NP * 3);
  hipLaunchKernelGGL(emd_sinkhorn, dim3(batch), dim3(256), 0, stream,
                     j1, j2, outp);
}